// Round 12
// baseline (378.045 us; speedup 1.0000x reference)
//
#include <hip/hip_runtime.h>
#include <math.h>

typedef unsigned int uint32;
typedef unsigned short u16;

typedef __bf16 bf16x8 __attribute__((ext_vector_type(8)));
typedef float f32x4 __attribute__((ext_vector_type(4)));

// ---------------- workspace layout (float indices) ----------------
#define OFF_STATS 0        // 48: sum,sumsq per (t=q/k/v, b, g)
#define OFF_MUSR  64       // 48: mu, rsigma (k/v gids only now)
#define OFF_L     128      // 512: softmax denominators per (b,c)
#define OFF_MROW  640      // (unused, kept for layout)
#define OFF_MAXV  1280     // (unused)
#define OFF_MINV  1792     // (unused)
#define OFF_CTX   2048     // 32768: raw context [b,h][d][e]
#define OFF_MBT   34816    // M' as bf16 [b][co][c'] : 131072 u16 = 65536 float slots
#define OFF_KB    165888   // 512: K_b
#define OFF_Z     167936   // z as bf16: 16777216 u16 = 8388608 float slots
#define OFF_DG    8556544  // 196608: dg conv output (pre-bias)
#define OFF_CTXP  8753152  // 64*8*4096 ctx partials (part mode)
#define OFF_LP    10850304 // 64*8*64 L partials
#define OFF_DGP   8753152  // 32*196608 fp32 dg partials (aliases CTXP/LP, consumed earlier)
#define WS_PART_FLOATS 15044608

__device__ __forceinline__ float bf2f(u16 h){ return __uint_as_float(((uint32)h)<<16); }
__device__ __forceinline__ u16 f2bf(float f){ uint32 u=__float_as_uint(f); return (u16)((u + 0x7fffu + ((u>>16)&1u))>>16); }

// ---------------- 1. stats: sum/sumsq per group, k and v ONLY ----------------
__global__ __launch_bounds__(512) void k_stats(const float* __restrict__ k,
                                               const float* __restrict__ v, float* __restrict__ ws){
  int gid8 = blockIdx.x >> 6;    // 0..15 (k:0-7, v:8-15)
  int chunk = blockIdx.x & 63;   // row within group
  int gid = 8 + gid8;            // workspace gid 8..23
  const float* src = (gid8 < 8)? k : v;
  int bg = gid8 & 7;
  const float* base = src + (size_t)bg*2097152 + (size_t)chunk*32768;
  int tid = threadIdx.x;
  float s=0.f, ss=0.f;
  #pragma unroll
  for (int it=0; it<8; ++it){
    float4 x = *(const float4*)(base + it*4096 + tid*8);
    float4 y = *(const float4*)(base + it*4096 + tid*8 + 4);
    s += ((x.x+x.y)+(x.z+x.w)) + ((y.x+y.y)+(y.z+y.w));
    ss = fmaf(x.x,x.x, fmaf(x.y,x.y, fmaf(x.z,x.z, fmaf(x.w,x.w, ss))));
    ss = fmaf(y.x,y.x, fmaf(y.y,y.y, fmaf(y.z,y.z, fmaf(y.w,y.w, ss))));
  }
  for (int o=32;o>0;o>>=1){
    s  += __shfl_down(s,o);  ss += __shfl_down(ss,o);
  }
  __shared__ float rsum[8], rssq[8];
  int w = tid>>6;
  if ((tid&63)==0){ rsum[w]=s; rssq[w]=ss; }
  __syncthreads();
  if (tid==0){
    float fs = ((rsum[0]+rsum[1])+(rsum[2]+rsum[3])) + ((rsum[4]+rsum[5])+(rsum[6]+rsum[7]));
    float fq = ((rssq[0]+rssq[1])+(rssq[2]+rssq[3])) + ((rssq[4]+rssq[5])+(rssq[6]+rssq[7]));
    atomicAdd(&ws[OFF_STATS + gid*2],   fs);
    atomicAdd(&ws[OFF_STATS + gid*2+1], fq);
  }
}

// ---------------- 2. finalize: mu/rsigma for k and v groups ----------------
__global__ void k_finalize(float* __restrict__ ws){
  int tid = threadIdx.x;
  if (tid >= 8 && tid < 24){
    float s=ws[OFF_STATS+2*tid], ss=ws[OFF_STATS+2*tid+1];
    const float inv = 1.f/2097152.f;
    float mu = s*inv;
    float var = ss*inv - mu*mu;
    ws[OFF_MUSR+2*tid]=mu; ws[OFF_MUSR+2*tid+1]=rsqrtf(var+1e-5f);
  }
}

// ---------------- 3. context via MFMA: ctx[d][e] = sum_n ek[d][n]*nv[e][n]; also L ----------------
__device__ __forceinline__ float4 expaff(float4 x, float a, float b, float& s){
  float4 e;
  e.x=__expf(fmaf(x.x,a,b)); e.y=__expf(fmaf(x.y,a,b));
  e.z=__expf(fmaf(x.z,a,b)); e.w=__expf(fmaf(x.w,a,b));
  s += (e.x+e.y)+(e.z+e.w);
  return e;
}
__device__ __forceinline__ float4 aff4(float4 x, float a, float b){
  return make_float4(fmaf(x.x,a,b), fmaf(x.y,a,b), fmaf(x.z,a,b), fmaf(x.w,a,b));
}
__device__ __forceinline__ bf16x8 cvt8(float4 a, float4 b){
  bf16x8 r;
  r[0]=(__bf16)a.x; r[1]=(__bf16)a.y; r[2]=(__bf16)a.z; r[3]=(__bf16)a.w;
  r[4]=(__bf16)b.x; r[5]=(__bf16)b.y; r[6]=(__bf16)b.z; r[7]=(__bf16)b.w;
  return r;
}

__global__ __launch_bounds__(256) void k_ctx(const float* __restrict__ qq,
                                             const float* __restrict__ kk, const float* __restrict__ vv,
                                             const float* __restrict__ gw, const float* __restrict__ gb,
                                             float* __restrict__ ws, int usePart){
  int tid = threadIdx.x;
  if (blockIdx.y >= 8){
    // ---- fused q-scan: 2 rows (256 KB) per block ----
    int sblk = (blockIdx.y - 8)*64 + blockIdx.x;   // 0..255
    int row0 = sblk*2;                             // rows 2s, 2s+1 (same batch+group)
    int half = tid>>7, l = tid&127;
    const float* p = qq + (size_t)(row0+half)*32768 + l*4;
    float s=0.f, ss=0.f;
    #pragma unroll 8
    for (int it=0; it<64; ++it){
      float4 x = *(const float4*)(p + it*512);
      s += (x.x+x.y)+(x.z+x.w);
      ss = fmaf(x.x,x.x, fmaf(x.y,x.y, fmaf(x.z,x.z, fmaf(x.w,x.w, ss))));
    }
    for (int o=32;o>0;o>>=1){ s += __shfl_down(s,o); ss += __shfl_down(ss,o); }
    __shared__ float rs_[4], rq_[4];
    if ((tid&63)==0){ rs_[tid>>6]=s; rq_[tid>>6]=ss; }
    __syncthreads();
    if (tid==0){
      int gid = (row0>>8)*4 + ((row0>>6)&3);       // b*4 + g
      atomicAdd(&ws[OFF_STATS + 2*gid],   (rs_[0]+rs_[1])+(rs_[2]+rs_[3]));
      atomicAdd(&ws[OFF_STATS + 2*gid+1], (rq_[0]+rq_[1])+(rq_[2]+rq_[3]));
    }
    return;
  }

  int chunk = blockIdx.x;  // 64 chunks x 512 tokens
  int bh = blockIdx.y; int b=bh>>2, h=bh&3;
  int lane = tid & 63, wv = tid >> 6;
  int m16 = lane & 15, quad = lane >> 4;
  int dhalf = wv >> 1, ehalf = wv & 1;

  int gik = 8+bh, giv = 16+bh;
  float muk=ws[OFF_MUSR+2*gik], rsk=ws[OFF_MUSR+2*gik+1];
  float muv=ws[OFF_MUSR+2*giv], rsv=ws[OFF_MUSR+2*giv+1];
  float akr[2], bmkr[2], avr[2], bvvr[2];
  #pragma unroll
  for (int t=0;t<2;++t){
    int c = h*64 + dhalf*32 + t*16 + m16;
    float a = rsk*gw[c];
    akr[t]=a; bmkr[t]=gb[c]-muk*a;     // no row-max subtraction: cancels in weff=s/L
  }
  #pragma unroll
  for (int t=0;t<2;++t){
    int c = h*64 + ehalf*32 + t*16 + m16;
    float a = rsv*gw[c];
    avr[t]=a; bvvr[t]=gb[c]-muv*a;
  }

  const float* kb = kk + (size_t)b*8388608 + (size_t)h*2097152;
  const float* vb = vv + (size_t)b*8388608 + (size_t)h*2097152;
  int nb0 = chunk*512;
  const float* kp[2]; const float* vp[2];
  kp[0] = kb + (size_t)(dhalf*32 + m16)*32768 + nb0 + quad*8;
  kp[1] = kp[0] + (size_t)16*32768;
  vp[0] = vb + (size_t)(ehalf*32 + m16)*32768 + nb0 + quad*8;
  vp[1] = vp[0] + (size_t)16*32768;

  f32x4 acc[2][2];
  #pragma unroll
  for (int i=0;i<2;++i){
    #pragma unroll
    for (int j=0;j<2;++j) acc[i][j] = 0.f;
  }
  float lsum[2] = {0.f, 0.f};

#define KCTX_LOAD(DK, DV, OFFS) do { \
    _Pragma("unroll") \
    for (int t=0;t<2;++t){ \
      DK[t][0] = *(const float4*)(kp[t] + (OFFS)); \
      DK[t][1] = *(const float4*)(kp[t] + (OFFS) + 4); \
      DV[t][0] = *(const float4*)(vp[t] + (OFFS)); \
      DV[t][1] = *(const float4*)(vp[t] + (OFFS) + 4); \
    } } while(0)

#define KCTX_STEP(SK, SV) do { \
    bf16x8 afr[2], bfr[2]; \
    _Pragma("unroll") \
    for (int t=0;t<2;++t){ \
      float4 e0 = expaff(SK[t][0], akr[t], bmkr[t], lsum[t]); \
      float4 e1 = expaff(SK[t][1], akr[t], bmkr[t], lsum[t]); \
      afr[t] = cvt8(e0,e1); \
      float4 v0 = aff4(SV[t][0], avr[t], bvvr[t]); \
      float4 v1 = aff4(SV[t][1], avr[t], bvvr[t]); \
      bfr[t] = cvt8(v0,v1); \
    } \
    _Pragma("unroll") \
    for (int i=0;i<2;++i){ \
      _Pragma("unroll") \
      for (int j=0;j<2;++j) \
        acc[i][j] = __builtin_amdgcn_mfma_f32_16x16x32_bf16(afr[i], bfr[j], acc[i][j], 0, 0, 0); \
    } } while(0)

  float4 ka[2][2], va[2][2];
  KCTX_LOAD(ka, va, 0);
  for (int s=0; s<15; ++s){
    float4 kn[2][2], vn[2][2];
    KCTX_LOAD(kn, vn, (s+1)*32);
    KCTX_STEP(ka, va);
    #pragma unroll
    for (int t=0;t<2;++t){
      ka[t][0]=kn[t][0]; ka[t][1]=kn[t][1];
      va[t][0]=vn[t][0]; va[t][1]=vn[t][1];
    }
  }
  KCTX_STEP(ka, va);
#undef KCTX_LOAD
#undef KCTX_STEP

  // L reduce: lanes (m16, m16+16, m16+32, m16+48) hold disjoint token subsets
  #pragma unroll
  for (int t=0;t<2;++t){
    lsum[t] += __shfl_down(lsum[t], 16);
    lsum[t] += __shfl_down(lsum[t], 32);
  }

  if (usePart){
    float* cp = ws + OFF_CTXP + (size_t)(chunk*8+bh)*4096;
    #pragma unroll
    for (int i=0;i<2;++i){
      #pragma unroll
      for (int j=0;j<2;++j){
        int row0 = dhalf*32 + i*16 + quad*4;
        int col  = ehalf*32 + j*16 + m16;
        #pragma unroll
        for (int r=0;r<4;++r)
          cp[(row0+r)*64 + col] = acc[i][j][r];
      }
    }
    if (ehalf==0 && quad==0){
      #pragma unroll
      for (int t=0;t<2;++t)
        ws[OFF_LP + (chunk*8+bh)*64 + dhalf*32 + t*16 + m16] = lsum[t];
    }
  } else {
    float* cp = ws + OFF_CTX + (size_t)bh*4096;
    #pragma unroll
    for (int i=0;i<2;++i){
      #pragma unroll
      for (int j=0;j<2;++j){
        int row0 = dhalf*32 + i*16 + quad*4;
        int col  = ehalf*32 + j*16 + m16;
        #pragma unroll
        for (int r=0;r<4;++r)
          atomicAdd(&cp[(row0+r)*64 + col], acc[i][j][r]);
      }
    }
    if (ehalf==0 && quad==0){
      #pragma unroll
      for (int t=0;t<2;++t)
        atomicAdd(&ws[OFF_L + bh*64 + dhalf*32 + t*16 + m16], lsum[t]);
    }
  }
}

// ---------------- 3b. reduce ctx + L partials ----------------
__global__ void k_ctxred(float* __restrict__ ws){
  int i = blockIdx.x*256 + threadIdx.x;
  if (i < 32768){
    float s = 0.f;
    const float* p = ws + OFF_CTXP + i;
    #pragma unroll 8
    for (int c=0;c<64;++c) s += p[(size_t)c*32768];
    ws[OFF_CTX + i] = s;
  } else if (i < 33280){
    int j = i - 32768;
    float s=0.f; const float* p = ws + OFF_LP + j;
    #pragma unroll 8
    for (int c=0;c<64;++c) s += p[c*512];
    ws[OFF_L + j] = s;
  }
}

// ---------------- 4. build M' (bf16, [b][co][c']) and K_b ----------------
__global__ __launch_bounds__(256) void k_weff(const float* __restrict__ w1, const float* __restrict__ ob,
                                              const float* __restrict__ gw, const float* __restrict__ gb,
                                              float* __restrict__ ws){
  int co = blockIdx.x; int b = blockIdx.y;
  int cp = threadIdx.x;
  int hp = cp>>6, dp = cp&63;
  const float* ctx = ws + OFF_CTX + (size_t)(b*4+hp)*4096 + dp*64;
  const float* w1p = w1 + co*256 + hp*64;
  float s = 0.f;
  #pragma unroll 8
  for (int e=0;e<64;++e) s = fmaf(w1p[e], ctx[e], s);
  float L = ws[OFF_L + b*256 + cp];
  float weff = s / L;
  int gi = b*4 + hp;                 // q stats (raw sums)
  float sq_  = ws[OFF_STATS + 2*gi];
  float sqq_ = ws[OFF_STATS + 2*gi + 1];
  const float invN = 1.f/2097152.f;
  float mu = sq_*invN;
  float rs = rsqrtf(sqq_*invN - mu*mu + 1e-5f);
  float aq = rs*gw[cp]; float bq = gb[cp] - mu*aq;
  // M' WITHOUT identity: residual q added in fp32 in k_z epilogue
  u16* mbp = (u16*)(ws + OFF_MBT);
  mbp[(size_t)b*65536 + (size_t)co*256 + cp] = f2bf(weff*aq);
  float kp = weff*bq;
  for (int o=32;o>0;o>>=1) kp += __shfl_down(kp,o);
  __shared__ float red[4];
  if ((cp&63)==0) red[cp>>6]=kp;
  __syncthreads();
  if (cp==0) ws[OFF_KB + b*256 + co] = ob[co] + ((red[0]+red[1])+(red[2]+red[3]));
}

// ---------------- 5. z = q + M' q + K_b  (MFMA bf16), z -> bf16 ----------------
// A-fragments read DIRECTLY from global (M' is 128 KB, L2-resident; aligned 16 B reads).
// B-stage (q transpose -> bf16 LDS) double-buffered: next tile's loads issue before
// this tile's MFMA, one barrier per tile (5 total vs 8). Same LDS budget (36864 B).
__global__ __launch_bounds__(256, 4) void k_z(const float* __restrict__ q, float* __restrict__ ws){
  extern __shared__ char smem[];
  u16* Bs = (u16*)smem;                 // 2 x 128*72*2 = 36864 B (double buffer)
  u16* Cs = (u16*)smem;                 // epilogue alias: 128*136*2 = 34816 B
  int nt = blockIdx.x, cot = blockIdx.y, b = blockIdx.z;
  int n0 = nt*128, co0 = cot*128;
  int tid = threadIdx.x;
  int lane = tid & 63, wv = tid >> 6;
  int m16 = lane & 15, quad = lane >> 4;
  int wco = (wv>>1)*64, wn = (wv&1)*64;
  const u16* mb = (const u16*)(ws + OFF_MBT) + (size_t)b*65536;
  const float* qb = q + (size_t)b*8388608;
  f32x4 acc[4][4];
  #pragma unroll
  for (int i=0;i<4;++i){
    #pragma unroll
    for (int j=0;j<4;++j) acc[i][j] = 0.f;
  }
  int r2 = tid>>1, seg = tid&1;
  int nq = tid & 31, cp0 = tid >> 5;

#define KZ_STAGE(BUF, KT) do { \
    _Pragma("unroll") \
    for (int p=0;p<4;++p){ \
      int cpair = cp0 + 8*p; \
      int c = (KT)*64 + 2*cpair; \
      const float* q0 = qb + (size_t)c*32768 + n0 + nq; \
      const float* q1 = q0 + 32768; \
      _Pragma("unroll") \
      for (int i=0;i<4;++i){ \
        float a  = q0[32*i]; \
        float bb = q1[32*i]; \
        uint32 dw = (uint32)f2bf(a) | ((uint32)f2bf(bb)<<16); \
        *(uint32*)(Bs + (BUF)*9216 + (nq+32*i)*72 + 2*cpair) = dw; \
      } \
    } } while(0)

  KZ_STAGE(0, 0);
  __syncthreads();
  for (int kt=0; kt<4; ++kt){
    int buf = kt & 1;
    if (kt < 3) KZ_STAGE(buf^1, kt+1);
    #pragma unroll
    for (int ks=0; ks<2; ++ks){
      bf16x8 af[4], bfr[4];
      #pragma unroll
      for (int i=0;i<4;++i)
        af[i] = *(const bf16x8*)(mb + (size_t)(co0 + wco + i*16 + m16)*256 + kt*64 + ks*32 + quad*8);
      #pragma unroll
      for (int j=0;j<4;++j)
        bfr[j] = *(const bf16x8*)(Bs + buf*9216 + (wn + j*16 + m16)*72 + ks*32 + quad*8);
      #pragma unroll
      for (int i=0;i<4;++i){
        #pragma unroll
        for (int j=0;j<4;++j)
          acc[i][j] = __builtin_amdgcn_mfma_f32_16x16x32_bf16(af[i], bfr[j], acc[i][j], 0, 0, 0);
      }
    }
    __syncthreads();
  }
#undef KZ_STAGE

  // epilogue: acc -> Cs (bf16, [co][n]), then coalesced read-back + fp32 q residual + Kb
  #pragma unroll
  for (int i=0;i<4;++i){
    #pragma unroll
    for (int r=0;r<4;++r){
      int row = wco + i*16 + quad*4 + r;
      #pragma unroll
      for (int j=0;j<4;++j)
        Cs[row*136 + wn + j*16 + m16] = f2bf(acc[i][j][r]);
    }
  }
  __syncthreads();
  {
    int co = co0 + r2;
    float kbv = ws[OFF_KB + b*256 + co];
    u16* zp = (u16*)(ws + OFF_Z) + (size_t)b*8388608 + (size_t)co*32768 + n0 + seg*64;
    const float* qr = qb + (size_t)co*32768 + n0 + seg*64;
    #pragma unroll
    for (int ch=0; ch<8; ++ch){
      uint4 cv = *(const uint4*)(Cs + r2*136 + seg*64 + ch*8);
      float4 qa = *(const float4*)(qr + ch*8);
      float4 qc = *(const float4*)(qr + ch*8 + 4);
      float z0 = qa.x + bf2f((u16)(cv.x&0xffff)) + kbv;
      float z1 = qa.y + bf2f((u16)(cv.x>>16))    + kbv;
      float z2 = qa.z + bf2f((u16)(cv.y&0xffff)) + kbv;
      float z3 = qa.w + bf2f((u16)(cv.y>>16))    + kbv;
      float z4 = qc.x + bf2f((u16)(cv.z&0xffff)) + kbv;
      float z5 = qc.y + bf2f((u16)(cv.z>>16))    + kbv;
      float z6 = qc.z + bf2f((u16)(cv.w&0xffff)) + kbv;
      float z7 = qc.w + bf2f((u16)(cv.w>>16))    + kbv;
      uint4 u;
      u.x = (uint32)f2bf(z0) | ((uint32)f2bf(z1)<<16);
      u.y = (uint32)f2bf(z2) | ((uint32)f2bf(z3)<<16);
      u.z = (uint32)f2bf(z4) | ((uint32)f2bf(z5)<<16);
      u.w = (uint32)f2bf(z6) | ((uint32)f2bf(z7)<<16);
      *(uint4*)(zp + ch*8) = u;
    }
  }
}

// ---------------- 6. dg conv: 3x3x3, 256 -> 3, pad 1; register-direct, no im2col ----------------
// thread = (wt, hy, dx): one 16-wide w-row at (d0+dx, h0+hy), 3 out channels.
// 16-wide-per-thread is load-bearing (R7: 8-wide = 12x HBM traffic).
// 32 splits x 8 ci, fp32 partials: best stable measurement (R6/R9: 64.4-65.7 us);
// 64-split/bf16 variant was not reliably faster (<=62 and 75 across two runs) — occupancy
// is NOT this kernel's limiter (two failed occupancy attacks, R7 + R11).
__global__ __launch_bounds__(256) void k_dg(const float* __restrict__ dgw, float* __restrict__ ws, int usePart){
  int tile = blockIdx.x;        // 0..7
  int split = blockIdx.y;       // 0..31 (8 ci each)
  int b = blockIdx.z;
  int d0 = (tile>>1)*8, h0=(tile&1)*16;
  int tid = threadIdx.x;
  int wt = tid&1, hy=(tid>>1)&15, dx=tid>>5;
  int d = d0+dx, h = h0+hy, w0 = wt*16;
  int cbeg = split*8;
  __shared__ float wss[8][27][4];     // [ci][tap][{o0,o1,o2,pad}]
  for (int i=tid;i<864;i+=256){
    int ci = i/108; int r = i - ci*108; int tap = r>>2; int o = r&3;
    wss[ci][tap][o] = (o<3)? dgw[o*6912 + (cbeg+ci)*27 + tap] : 0.f;
  }
  __syncthreads();
  const u16* zp = (const u16*)(ws+OFF_Z) + (size_t)b*8388608;
  float acc[3][16];
  #pragma unroll
  for (int o=0;o<3;++o){
    #pragma unroll
    for (int j=0;j<16;++j) acc[o][j]=0.f;
  }
  for (int ci=0; ci<8; ++ci){
    const u16* zc = zp + (size_t)(cbeg+ci)*32768;
    #pragma unroll
    for (int kd=0;kd<3;++kd){
      int gd = d+kd-1;
      #pragma unroll
      for (int kh=0;kh<3;++kh){
        int gh = h+kh-1;
        bool rv = (gd>=0) & (gd<32) & (gh>=0) & (gh<32);
        const u16* rowp = zc + gd*1024 + gh*32 + w0;
        // loads stay inside ws even when gd/gh step out by one plane/row
        uint4 u0 = *(const uint4*)(rowp);
        uint4 u1 = *(const uint4*)(rowp+8);
        u16 le = (wt==0)? (u16)0 : rowp[-1];
        u16 ri = (wt==1)? (u16)0 : rowp[16];
        if (!rv){ u0 = make_uint4(0,0,0,0); u1 = make_uint4(0,0,0,0); le = 0; ri = 0; }
        float r[18];
        r[0]  = bf2f(le);
        r[1]  = bf2f((u16)(u0.x&0xffff)); r[2]  = bf2f((u16)(u0.x>>16));
        r[3]  = bf2f((u16)(u0.y&0xffff)); r[4]  = bf2f((u16)(u0.y>>16));
        r[5]  = bf2f((u16)(u0.z&0xffff)); r[6]  = bf2f((u16)(u0.z>>16));
        r[7]  = bf2f((u16)(u0.w&0xffff)); r[8]  = bf2f((u16)(u0.w>>16));
        r[9]  = bf2f((u16)(u1.x&0xffff)); r[10] = bf2f((u16)(u1.x>>16));
        r[11] = bf2f((u16)(u1.y&0xffff)); r[12] = bf2f((u16)(u1.y>>16));
        r[13] = bf2f((u16)(u1.z&0xffff)); r[14] = bf2f((u16)(u1.z>>16));
        r[15] = bf2f((u16)(u1.w&0xffff)); r[16] = bf2f((u16)(u1.w>>16));
        r[17] = bf2f(ri);
        #pragma unroll
        for (int kw=0;kw<3;++kw){
          float4 wv = *(const float4*)&wss[ci][kd*9+kh*3+kw][0];
          #pragma unroll
          for (int j=0;j<16;++j){
            acc[0][j]=fmaf(r[j+kw],wv.x,acc[0][j]);
            acc[1][j]=fmaf(r[j+kw],wv.y,acc[1][j]);
            acc[2][j]=fmaf(r[j+kw],wv.z,acc[2][j]);
          }
        }
      }
    }
  }
  if (usePart){
    float* op = ws + OFF_DGP + (size_t)split*196608 + (size_t)b*98304;
    #pragma unroll
    for (int o=0;o<3;++o){
      int base = o*32768 + d*1024 + h*32 + w0;
      *(float4*)&op[base+0]  = make_float4(acc[o][0],acc[o][1],acc[o][2],acc[o][3]);
      *(float4*)&op[base+4]  = make_float4(acc[o][4],acc[o][5],acc[o][6],acc[o][7]);
      *(float4*)&op[base+8]  = make_float4(acc[o][8],acc[o][9],acc[o][10],acc[o][11]);
      *(float4*)&op[base+12] = make_float4(acc[o][12],acc[o][13],acc[o][14],acc[o][15]);
    }
  } else {
    float* op = ws + OFF_DG + (size_t)b*98304;
    #pragma unroll
    for (int o=0;o<3;++o){
      #pragma unroll
      for (int j=0;j<16;++j)
        atomicAdd(&op[o*32768 + d*1024 + h*32 + w0 + j], acc[o][j]);
    }
  }
}

__global__ void k_dgred(float* __restrict__ ws){
  int i = blockIdx.x*256 + threadIdx.x; // < 196608
  float s = 0.f;
  const float* p = ws + OFF_DGP + i;
  #pragma unroll 8
  for (int c=0;c<32;++c) s += p[(size_t)c*196608];
  ws[OFF_DG + i] = s;
}

// ---------------- 7. upsample x2 nearest + 3x3x3 conv (3->3), pad 1 ----------------
__global__ __launch_bounds__(256) void k_up(const float* __restrict__ dgb, const float* __restrict__ nlw,
                                            const float* __restrict__ nlb, const float* __restrict__ ws,
                                            float* __restrict__ out){
  int b = blockIdx.y; int tileIdx = blockIdx.x;
  int zt0 = (tileIdx&7)*8, yt0 = ((tileIdx>>3)&7)*8, xt0 = (tileIdx>>6)*4;
  int sx0 = (xt0>>1)-1, sy0 = (yt0>>1)-1, sz0 = (zt0>>1)-1;
  __shared__ float ds[3][4][6][6];
  __shared__ float wl[243];
  const float* dgp = ws + OFF_DG + (size_t)b*98304;
  for (int i=threadIdx.x; i<432; i+=256){
    int ch = i/144; int r = i-ch*144; int sx=r/36; int rr=r-sx*36; int sy=rr/6; int sz=rr-sy*6;
    int gx = sx0+sx, gy = sy0+sy, gz = sz0+sz;
    float v=0.f;
    if (gx>=0&&gx<32&&gy>=0&&gy<32&&gz>=0&&gz<32) v = dgp[ch*32768 + gx*1024 + gy*32 + gz] + dgb[ch];
    ds[ch][sx][sy][sz] = v;
  }
  for (int i=threadIdx.x;i<243;i+=256) wl[i] = nlw[i];
  __syncthreads();
  int zt = threadIdx.x&7, yt=(threadIdx.x>>3)&7, xt=threadIdx.x>>6;
  int x = xt0+xt, y=yt0+yt, zc=zt0+zt;
  float a0=nlb[0], a1=nlb[1], a2=nlb[2];
  #pragma unroll
  for (int i=0;i<3;++i){
    #pragma unroll
    for (int kd=0;kd<3;++kd){
      int sxi = ((x+kd-1)>>1) - sx0;
      #pragma unroll
      for (int kh=0;kh<3;++kh){
        int syi = ((y+kh-1)>>1) - sy0;
        #pragma unroll
        for (int kw=0;kw<3;++kw){
          int szi = ((zc+kw-1)>>1) - sz0;
          float vv = ds[i][sxi][syi][szi];
          int tap = kd*9+kh*3+kw;
          a0 = fmaf(vv, wl[i*27+tap],      a0);
          a1 = fmaf(vv, wl[81+i*27+tap],   a1);
          a2 = fmaf(vv, wl[162+i*27+tap],  a2);
        }
      }
    }
  }
  size_t o0 = (size_t)b*786432 + (size_t)x*4096 + y*64 + zc;
  out[o0] = a0; out[o0+262144] = a1; out[o0+524288] = a2;
}

// ---------------- launch ----------------
extern "C" void kernel_launch(void* const* d_in, const int* in_sizes, int n_in,
                              void* d_out, int out_size, void* d_ws, size_t ws_size,
                              hipStream_t stream){
  const float* q    = (const float*)d_in[0];
  const float* k    = (const float*)d_in[1];
  const float* v    = (const float*)d_in[2];
  const float* gnw  = (const float*)d_in[3];
  const float* gnb  = (const float*)d_in[4];
  const float* outw = (const float*)d_in[5];
  const float* outb = (const float*)d_in[6];
  const float* dgw  = (const float*)d_in[7];
  const float* dgb  = (const float*)d_in[8];
  const float* nlw  = (const float*)d_in[9];
  const float* nlb  = (const float*)d_in[10];
  float* out = (float*)d_out;
  float* ws  = (float*)d_ws;
  int usePart = (ws_size >= (size_t)WS_PART_FLOATS*4) ? 1 : 0;

  (void)hipMemsetAsync(ws, 0, 139264, stream);                       // stats..ctx region
  (void)hipMemsetAsync((void*)(ws + OFF_DG), 0, 196608*4, stream);   // dg final (atomic fallback)

  k_stats   <<<dim3(1024),   dim3(512), 0, stream>>>(k,v,ws);
  k_finalize<<<dim3(1),      dim3(32),  0, stream>>>(ws);
  k_ctx     <<<dim3(64,12),  dim3(256), 0, stream>>>(q,k,v,gnw,gnb,ws,usePart);
  if (usePart) k_ctxred<<<dim3(130), dim3(256), 0, stream>>>(ws);
  k_weff    <<<dim3(256,2),  dim3(256), 0, stream>>>(outw,outb,gnw,gnb,ws);
  k_z       <<<dim3(256,2,2),dim3(256), 36864, stream>>>(q,ws);
  k_dg      <<<dim3(8,32,2), dim3(256), 0, stream>>>(dgw,ws,usePart);
  if (usePart) k_dgred<<<dim3(768), dim3(256), 0, stream>>>(ws);
  k_up      <<<dim3(1024,2), dim3(256), 0, stream>>>(dgb,nlw,nlb,ws,out);
}

// Round 13
// 340.544 us; speedup vs baseline: 1.1101x; 1.1101x over previous
//
#include <hip/hip_runtime.h>
#include <math.h>

typedef unsigned int uint32;
typedef unsigned short u16;

typedef __bf16 bf16x8 __attribute__((ext_vector_type(8)));
typedef float f32x4 __attribute__((ext_vector_type(4)));

// ---------------- workspace layout (float indices) ----------------
#define OFF_STATS 0        // 48: sum,sumsq per (t=q/k/v, b, g)
#define OFF_MUSR  64       // 48: mu, rsigma (k/v gids only now)
#define OFF_L     128      // 512: softmax denominators per (b,c)
#define OFF_CTX   2048     // 32768: raw context [b,h][d][e]
#define OFF_MBT   34816    // M' as bf16 [b][co][c'] : 131072 u16 = 65536 float slots
#define OFF_WT    100352   // W' as bf16 [96][256] : 24576 u16 = 12288 float slots
#define OFF_KB    165888   // 512: K_b
#define OFF_Z     167936   // z as bf16: 16777216 u16 = 8388608 float slots
#define OFF_DG    8556544  // 196608: dg conv output (pre-bias)
#define OFF_CTXP  8753152  // 64*8*4096 ctx partials (part mode)
#define OFF_LP    10850304 // 64*8*64 L partials
#define OFF_YP    8753152  // y_pre fp32 [b][96][32768] = 6291456 floats (aliases CTXP/LP, consumed earlier)
#define WS_PART_FLOATS 15044608

__device__ __forceinline__ float bf2f(u16 h){ return __uint_as_float(((uint32)h)<<16); }
__device__ __forceinline__ u16 f2bf(float f){ uint32 u=__float_as_uint(f); return (u16)((u + 0x7fffu + ((u>>16)&1u))>>16); }

// ---------------- 1. stats: sum/sumsq per group, k and v ONLY ----------------
__global__ __launch_bounds__(512) void k_stats(const float* __restrict__ k,
                                               const float* __restrict__ v, float* __restrict__ ws){
  int gid8 = blockIdx.x >> 6;    // 0..15 (k:0-7, v:8-15)
  int chunk = blockIdx.x & 63;   // row within group
  int gid = 8 + gid8;            // workspace gid 8..23
  const float* src = (gid8 < 8)? k : v;
  int bg = gid8 & 7;
  const float* base = src + (size_t)bg*2097152 + (size_t)chunk*32768;
  int tid = threadIdx.x;
  float s=0.f, ss=0.f;
  #pragma unroll
  for (int it=0; it<8; ++it){
    float4 x = *(const float4*)(base + it*4096 + tid*8);
    float4 y = *(const float4*)(base + it*4096 + tid*8 + 4);
    s += ((x.x+x.y)+(x.z+x.w)) + ((y.x+y.y)+(y.z+y.w));
    ss = fmaf(x.x,x.x, fmaf(x.y,x.y, fmaf(x.z,x.z, fmaf(x.w,x.w, ss))));
    ss = fmaf(y.x,y.x, fmaf(y.y,y.y, fmaf(y.z,y.z, fmaf(y.w,y.w, ss))));
  }
  for (int o=32;o>0;o>>=1){
    s  += __shfl_down(s,o);  ss += __shfl_down(ss,o);
  }
  __shared__ float rsum[8], rssq[8];
  int w = tid>>6;
  if ((tid&63)==0){ rsum[w]=s; rssq[w]=ss; }
  __syncthreads();
  if (tid==0){
    float fs = ((rsum[0]+rsum[1])+(rsum[2]+rsum[3])) + ((rsum[4]+rsum[5])+(rsum[6]+rsum[7]));
    float fq = ((rssq[0]+rssq[1])+(rssq[2]+rssq[3])) + ((rssq[4]+rssq[5])+(rssq[6]+rssq[7]));
    atomicAdd(&ws[OFF_STATS + gid*2],   fs);
    atomicAdd(&ws[OFF_STATS + gid*2+1], fq);
  }
}

// ---------------- 2. finalize: mu/rsigma for k and v groups ----------------
__global__ void k_finalize(float* __restrict__ ws){
  int tid = threadIdx.x;
  if (tid >= 8 && tid < 24){
    float s=ws[OFF_STATS+2*tid], ss=ws[OFF_STATS+2*tid+1];
    const float inv = 1.f/2097152.f;
    float mu = s*inv;
    float var = ss*inv - mu*mu;
    ws[OFF_MUSR+2*tid]=mu; ws[OFF_MUSR+2*tid+1]=rsqrtf(var+1e-5f);
  }
}

// ---------------- 2b. repack dg weights: W'[o*27+tap][ci] bf16 ----------------
__global__ void k_wt(const float* __restrict__ dgw, float* __restrict__ ws){
  int idx = blockIdx.x*256 + threadIdx.x; // < 24576
  int r = idx>>8, ci = idx&255;
  int o = r/27, tap = r - o*27;
  ((u16*)(ws + OFF_WT))[idx] = f2bf(dgw[o*6912 + ci*27 + tap]);
}

// ---------------- 3. context via MFMA: ctx[d][e] = sum_n ek[d][n]*nv[e][n]; also L ----------------
__device__ __forceinline__ float4 expaff(float4 x, float a, float b, float& s){
  float4 e;
  e.x=__expf(fmaf(x.x,a,b)); e.y=__expf(fmaf(x.y,a,b));
  e.z=__expf(fmaf(x.z,a,b)); e.w=__expf(fmaf(x.w,a,b));
  s += (e.x+e.y)+(e.z+e.w);
  return e;
}
__device__ __forceinline__ float4 aff4(float4 x, float a, float b){
  return make_float4(fmaf(x.x,a,b), fmaf(x.y,a,b), fmaf(x.z,a,b), fmaf(x.w,a,b));
}
__device__ __forceinline__ bf16x8 cvt8(float4 a, float4 b){
  bf16x8 r;
  r[0]=(__bf16)a.x; r[1]=(__bf16)a.y; r[2]=(__bf16)a.z; r[3]=(__bf16)a.w;
  r[4]=(__bf16)b.x; r[5]=(__bf16)b.y; r[6]=(__bf16)b.z; r[7]=(__bf16)b.w;
  return r;
}

__global__ __launch_bounds__(256) void k_ctx(const float* __restrict__ qq,
                                             const float* __restrict__ kk, const float* __restrict__ vv,
                                             const float* __restrict__ gw, const float* __restrict__ gb,
                                             float* __restrict__ ws, int usePart){
  int tid = threadIdx.x;
  if (blockIdx.y >= 8){
    // ---- fused q-scan: 2 rows (256 KB) per block ----
    int sblk = (blockIdx.y - 8)*64 + blockIdx.x;   // 0..255
    int row0 = sblk*2;                             // rows 2s, 2s+1 (same batch+group)
    int half = tid>>7, l = tid&127;
    const float* p = qq + (size_t)(row0+half)*32768 + l*4;
    float s=0.f, ss=0.f;
    #pragma unroll 8
    for (int it=0; it<64; ++it){
      float4 x = *(const float4*)(p + it*512);
      s += (x.x+x.y)+(x.z+x.w);
      ss = fmaf(x.x,x.x, fmaf(x.y,x.y, fmaf(x.z,x.z, fmaf(x.w,x.w, ss))));
    }
    for (int o=32;o>0;o>>=1){ s += __shfl_down(s,o); ss += __shfl_down(ss,o); }
    __shared__ float rs_[4], rq_[4];
    if ((tid&63)==0){ rs_[tid>>6]=s; rq_[tid>>6]=ss; }
    __syncthreads();
    if (tid==0){
      int gid = (row0>>8)*4 + ((row0>>6)&3);       // b*4 + g
      atomicAdd(&ws[OFF_STATS + 2*gid],   (rs_[0]+rs_[1])+(rs_[2]+rs_[3]));
      atomicAdd(&ws[OFF_STATS + 2*gid+1], (rq_[0]+rq_[1])+(rq_[2]+rq_[3]));
    }
    return;
  }

  int chunk = blockIdx.x;  // 64 chunks x 512 tokens
  int bh = blockIdx.y; int b=bh>>2, h=bh&3;
  int lane = tid & 63, wv = tid >> 6;
  int m16 = lane & 15, quad = lane >> 4;
  int dhalf = wv >> 1, ehalf = wv & 1;

  int gik = 8+bh, giv = 16+bh;
  float muk=ws[OFF_MUSR+2*gik], rsk=ws[OFF_MUSR+2*gik+1];
  float muv=ws[OFF_MUSR+2*giv], rsv=ws[OFF_MUSR+2*giv+1];
  float akr[2], bmkr[2], avr[2], bvvr[2];
  #pragma unroll
  for (int t=0;t<2;++t){
    int c = h*64 + dhalf*32 + t*16 + m16;
    float a = rsk*gw[c];
    akr[t]=a; bmkr[t]=gb[c]-muk*a;     // no row-max subtraction: cancels in weff=s/L
  }
  #pragma unroll
  for (int t=0;t<2;++t){
    int c = h*64 + ehalf*32 + t*16 + m16;
    float a = rsv*gw[c];
    avr[t]=a; bvvr[t]=gb[c]-muv*a;
  }

  const float* kb = kk + (size_t)b*8388608 + (size_t)h*2097152;
  const float* vb = vv + (size_t)b*8388608 + (size_t)h*2097152;
  int nb0 = chunk*512;
  const float* kp[2]; const float* vp[2];
  kp[0] = kb + (size_t)(dhalf*32 + m16)*32768 + nb0 + quad*8;
  kp[1] = kp[0] + (size_t)16*32768;
  vp[0] = vb + (size_t)(ehalf*32 + m16)*32768 + nb0 + quad*8;
  vp[1] = vp[0] + (size_t)16*32768;

  f32x4 acc[2][2];
  #pragma unroll
  for (int i=0;i<2;++i){
    #pragma unroll
    for (int j=0;j<2;++j) acc[i][j] = 0.f;
  }
  float lsum[2] = {0.f, 0.f};

#define KCTX_LOAD(DK, DV, OFFS) do { \
    _Pragma("unroll") \
    for (int t=0;t<2;++t){ \
      DK[t][0] = *(const float4*)(kp[t] + (OFFS)); \
      DK[t][1] = *(const float4*)(kp[t] + (OFFS) + 4); \
      DV[t][0] = *(const float4*)(vp[t] + (OFFS)); \
      DV[t][1] = *(const float4*)(vp[t] + (OFFS) + 4); \
    } } while(0)

#define KCTX_STEP(SK, SV) do { \
    bf16x8 afr[2], bfr[2]; \
    _Pragma("unroll") \
    for (int t=0;t<2;++t){ \
      float4 e0 = expaff(SK[t][0], akr[t], bmkr[t], lsum[t]); \
      float4 e1 = expaff(SK[t][1], akr[t], bmkr[t], lsum[t]); \
      afr[t] = cvt8(e0,e1); \
      float4 v0 = aff4(SV[t][0], avr[t], bvvr[t]); \
      float4 v1 = aff4(SV[t][1], avr[t], bvvr[t]); \
      bfr[t] = cvt8(v0,v1); \
    } \
    _Pragma("unroll") \
    for (int i=0;i<2;++i){ \
      _Pragma("unroll") \
      for (int j=0;j<2;++j) \
        acc[i][j] = __builtin_amdgcn_mfma_f32_16x16x32_bf16(afr[i], bfr[j], acc[i][j], 0, 0, 0); \
    } } while(0)

  float4 ka[2][2], va[2][2];
  KCTX_LOAD(ka, va, 0);
  for (int s=0; s<15; ++s){
    float4 kn[2][2], vn[2][2];
    KCTX_LOAD(kn, vn, (s+1)*32);
    KCTX_STEP(ka, va);
    #pragma unroll
    for (int t=0;t<2;++t){
      ka[t][0]=kn[t][0]; ka[t][1]=kn[t][1];
      va[t][0]=vn[t][0]; va[t][1]=vn[t][1];
    }
  }
  KCTX_STEP(ka, va);
#undef KCTX_LOAD
#undef KCTX_STEP

  // L reduce: lanes (m16, m16+16, m16+32, m16+48) hold disjoint token subsets
  #pragma unroll
  for (int t=0;t<2;++t){
    lsum[t] += __shfl_down(lsum[t], 16);
    lsum[t] += __shfl_down(lsum[t], 32);
  }

  if (usePart){
    float* cp = ws + OFF_CTXP + (size_t)(chunk*8+bh)*4096;
    #pragma unroll
    for (int i=0;i<2;++i){
      #pragma unroll
      for (int j=0;j<2;++j){
        int row0 = dhalf*32 + i*16 + quad*4;
        int col  = ehalf*32 + j*16 + m16;
        #pragma unroll
        for (int r=0;r<4;++r)
          cp[(row0+r)*64 + col] = acc[i][j][r];
      }
    }
    if (ehalf==0 && quad==0){
      #pragma unroll
      for (int t=0;t<2;++t)
        ws[OFF_LP + (chunk*8+bh)*64 + dhalf*32 + t*16 + m16] = lsum[t];
    }
  } else {
    float* cp = ws + OFF_CTX + (size_t)bh*4096;
    #pragma unroll
    for (int i=0;i<2;++i){
      #pragma unroll
      for (int j=0;j<2;++j){
        int row0 = dhalf*32 + i*16 + quad*4;
        int col  = ehalf*32 + j*16 + m16;
        #pragma unroll
        for (int r=0;r<4;++r)
          atomicAdd(&cp[(row0+r)*64 + col], acc[i][j][r]);
      }
    }
    if (ehalf==0 && quad==0){
      #pragma unroll
      for (int t=0;t<2;++t)
        atomicAdd(&ws[OFF_L + bh*64 + dhalf*32 + t*16 + m16], lsum[t]);
    }
  }
}

// ---------------- 3b. reduce ctx + L partials ----------------
__global__ void k_ctxred(float* __restrict__ ws){
  int i = blockIdx.x*256 + threadIdx.x;
  if (i < 32768){
    float s = 0.f;
    const float* p = ws + OFF_CTXP + i;
    #pragma unroll 8
    for (int c=0;c<64;++c) s += p[(size_t)c*32768];
    ws[OFF_CTX + i] = s;
  } else if (i < 33280){
    int j = i - 32768;
    float s=0.f; const float* p = ws + OFF_LP + j;
    #pragma unroll 8
    for (int c=0;c<64;++c) s += p[c*512];
    ws[OFF_L + j] = s;
  }
}

// ---------------- 4. build M' (bf16, [b][co][c']) and K_b ----------------
__global__ __launch_bounds__(256) void k_weff(const float* __restrict__ w1, const float* __restrict__ ob,
                                              const float* __restrict__ gw, const float* __restrict__ gb,
                                              float* __restrict__ ws){
  int co = blockIdx.x; int b = blockIdx.y;
  int cp = threadIdx.x;
  int hp = cp>>6, dp = cp&63;
  const float* ctx = ws + OFF_CTX + (size_t)(b*4+hp)*4096 + dp*64;
  const float* w1p = w1 + co*256 + hp*64;
  float s = 0.f;
  #pragma unroll 8
  for (int e=0;e<64;++e) s = fmaf(w1p[e], ctx[e], s);
  float L = ws[OFF_L + b*256 + cp];
  float weff = s / L;
  int gi = b*4 + hp;                 // q stats (raw sums)
  float sq_  = ws[OFF_STATS + 2*gi];
  float sqq_ = ws[OFF_STATS + 2*gi + 1];
  const float invN = 1.f/2097152.f;
  float mu = sq_*invN;
  float rs = rsqrtf(sqq_*invN - mu*mu + 1e-5f);
  float aq = rs*gw[cp]; float bq = gb[cp] - mu*aq;
  // M' WITHOUT identity: residual q added in fp32 in k_z epilogue
  u16* mbp = (u16*)(ws + OFF_MBT);
  mbp[(size_t)b*65536 + (size_t)co*256 + cp] = f2bf(weff*aq);
  float kp = weff*bq;
  for (int o=32;o>0;o>>=1) kp += __shfl_down(kp,o);
  __shared__ float red[4];
  if ((cp&63)==0) red[cp>>6]=kp;
  __syncthreads();
  if (cp==0) ws[OFF_KB + b*256 + co] = ob[co] + ((red[0]+red[1])+(red[2]+red[3]));
}

// ---------------- 5. z = q + M' q + K_b  (MFMA bf16), z -> bf16 ----------------
__global__ __launch_bounds__(256, 4) void k_z(const float* __restrict__ q, float* __restrict__ ws){
  extern __shared__ char smem[];
  u16* Bs = (u16*)smem;                 // 2 x 128*72*2 = 36864 B (double buffer)
  u16* Cs = (u16*)smem;                 // epilogue alias: 128*136*2 = 34816 B
  int nt = blockIdx.x, cot = blockIdx.y, b = blockIdx.z;
  int n0 = nt*128, co0 = cot*128;
  int tid = threadIdx.x;
  int lane = tid & 63, wv = tid >> 6;
  int m16 = lane & 15, quad = lane >> 4;
  int wco = (wv>>1)*64, wn = (wv&1)*64;
  const u16* mb = (const u16*)(ws + OFF_MBT) + (size_t)b*65536;
  const float* qb = q + (size_t)b*8388608;
  f32x4 acc[4][4];
  #pragma unroll
  for (int i=0;i<4;++i){
    #pragma unroll
    for (int j=0;j<4;++j) acc[i][j] = 0.f;
  }
  int r2 = tid>>1, seg = tid&1;
  int nq = tid & 31, cp0 = tid >> 5;

#define KZ_STAGE(BUF, KT) do { \
    _Pragma("unroll") \
    for (int p=0;p<4;++p){ \
      int cpair = cp0 + 8*p; \
      int c = (KT)*64 + 2*cpair; \
      const float* q0 = qb + (size_t)c*32768 + n0 + nq; \
      const float* q1 = q0 + 32768; \
      _Pragma("unroll") \
      for (int i=0;i<4;++i){ \
        float a  = q0[32*i]; \
        float bb = q1[32*i]; \
        uint32 dw = (uint32)f2bf(a) | ((uint32)f2bf(bb)<<16); \
        *(uint32*)(Bs + (BUF)*9216 + (nq+32*i)*72 + 2*cpair) = dw; \
      } \
    } } while(0)

  KZ_STAGE(0, 0);
  __syncthreads();
  for (int kt=0; kt<4; ++kt){
    int buf = kt & 1;
    if (kt < 3) KZ_STAGE(buf^1, kt+1);
    #pragma unroll
    for (int ks=0; ks<2; ++ks){
      bf16x8 af[4], bfr[4];
      #pragma unroll
      for (int i=0;i<4;++i)
        af[i] = *(const bf16x8*)(mb + (size_t)(co0 + wco + i*16 + m16)*256 + kt*64 + ks*32 + quad*8);
      #pragma unroll
      for (int j=0;j<4;++j)
        bfr[j] = *(const bf16x8*)(Bs + buf*9216 + (wn + j*16 + m16)*72 + ks*32 + quad*8);
      #pragma unroll
      for (int i=0;i<4;++i){
        #pragma unroll
        for (int j=0;j<4;++j)
          acc[i][j] = __builtin_amdgcn_mfma_f32_16x16x32_bf16(af[i], bfr[j], acc[i][j], 0, 0, 0);
      }
    }
    __syncthreads();
  }
#undef KZ_STAGE

  // epilogue: acc -> Cs (bf16, [co][n]), then coalesced read-back + fp32 q residual + Kb
  #pragma unroll
  for (int i=0;i<4;++i){
    #pragma unroll
    for (int r=0;r<4;++r){
      int row = wco + i*16 + quad*4 + r;
      #pragma unroll
      for (int j=0;j<4;++j)
        Cs[row*136 + wn + j*16 + m16] = f2bf(acc[i][j][r]);
    }
  }
  __syncthreads();
  {
    int co = co0 + r2;
    float kbv = ws[OFF_KB + b*256 + co];
    u16* zp = (u16*)(ws + OFF_Z) + (size_t)b*8388608 + (size_t)co*32768 + n0 + seg*64;
    const float* qr = qb + (size_t)co*32768 + n0 + seg*64;
    #pragma unroll
    for (int ch=0; ch<8; ++ch){
      uint4 cv = *(const uint4*)(Cs + r2*136 + seg*64 + ch*8);
      float4 qa = *(const float4*)(qr + ch*8);
      float4 qc = *(const float4*)(qr + ch*8 + 4);
      float z0 = qa.x + bf2f((u16)(cv.x&0xffff)) + kbv;
      float z1 = qa.y + bf2f((u16)(cv.x>>16))    + kbv;
      float z2 = qa.z + bf2f((u16)(cv.y&0xffff)) + kbv;
      float z3 = qa.w + bf2f((u16)(cv.y>>16))    + kbv;
      float z4 = qc.x + bf2f((u16)(cv.z&0xffff)) + kbv;
      float z5 = qc.y + bf2f((u16)(cv.z>>16))    + kbv;
      float z6 = qc.z + bf2f((u16)(cv.w&0xffff)) + kbv;
      float z7 = qc.w + bf2f((u16)(cv.w>>16))    + kbv;
      uint4 u;
      u.x = (uint32)f2bf(z0) | ((uint32)f2bf(z1)<<16);
      u.y = (uint32)f2bf(z2) | ((uint32)f2bf(z3)<<16);
      u.z = (uint32)f2bf(z4) | ((uint32)f2bf(z5)<<16);
      u.w = (uint32)f2bf(z6) | ((uint32)f2bf(z7)<<16);
      *(uint4*)(zp + ch*8) = u;
    }
  }
}

// ---------------- 6a. dg as MFMA GEMM: y_pre[r=o*27+tap][n] = sum_ci W'[r][ci] z[ci][n] ----------------
// Mirrors k_z structure exactly (A from global bf16 row-major, B via LDS transpose double-buffer).
// M=96 (2 wave-rows x 48), N tile = 128, K = 256 in 4 tiles of 64.
__global__ __launch_bounds__(256, 4) void k_dgm(float* __restrict__ ws){
  extern __shared__ char smem[];
  u16* Bs = (u16*)smem;                 // 2 x 128*72*2 = 36864 B
  int nt = blockIdx.x, b = blockIdx.y;
  int n0 = nt*128;
  int tid = threadIdx.x;
  int lane = tid & 63, wv = tid >> 6;
  int m16 = lane & 15, quad = lane >> 4;
  int wr = (wv>>1)*48, wc = (wv&1)*64;
  const u16* wt = (const u16*)(ws + OFF_WT);
  const u16* zb = (const u16*)(ws + OFF_Z) + (size_t)b*8388608;
  f32x4 acc[3][4];
  #pragma unroll
  for (int i=0;i<3;++i){
    #pragma unroll
    for (int j=0;j<4;++j) acc[i][j] = 0.f;
  }
  int nq = tid & 31, cp0 = tid >> 5;

#define DGM_STAGE(BUF, KT) do { \
    _Pragma("unroll") \
    for (int p=0;p<4;++p){ \
      int cpair = cp0 + 8*p; \
      int c = (KT)*64 + 2*cpair; \
      const u16* z0 = zb + (size_t)c*32768 + n0 + nq; \
      const u16* z1 = z0 + 32768; \
      _Pragma("unroll") \
      for (int i=0;i<4;++i){ \
        uint32 dw = (uint32)z0[32*i] | ((uint32)z1[32*i]<<16); \
        *(uint32*)(Bs + (BUF)*9216 + (nq+32*i)*72 + 2*cpair) = dw; \
      } \
    } } while(0)

  DGM_STAGE(0, 0);
  __syncthreads();
  for (int kt=0; kt<4; ++kt){
    int buf = kt & 1;
    if (kt < 3) DGM_STAGE(buf^1, kt+1);
    #pragma unroll
    for (int ks=0; ks<2; ++ks){
      bf16x8 af[3], bfr[4];
      #pragma unroll
      for (int i=0;i<3;++i)
        af[i] = *(const bf16x8*)(wt + (size_t)(wr + i*16 + m16)*256 + kt*64 + ks*32 + quad*8);
      #pragma unroll
      for (int j=0;j<4;++j)
        bfr[j] = *(const bf16x8*)(Bs + buf*9216 + (wc + j*16 + m16)*72 + ks*32 + quad*8);
      #pragma unroll
      for (int i=0;i<3;++i){
        #pragma unroll
        for (int j=0;j<4;++j)
          acc[i][j] = __builtin_amdgcn_mfma_f32_16x16x32_bf16(af[i], bfr[j], acc[i][j], 0, 0, 0);
      }
    }
    __syncthreads();
  }
#undef DGM_STAGE

  // store y_pre fp32 directly (row = wr + i*16 + quad*4 + r, col = wc + j*16 + m16)
  float* yp = ws + OFF_YP + (size_t)b*3145728;
  #pragma unroll
  for (int i=0;i<3;++i){
    #pragma unroll
    for (int j=0;j<4;++j){
      #pragma unroll
      for (int r=0;r<4;++r)
        yp[(size_t)(wr + i*16 + quad*4 + r)*32768 + n0 + wc + j*16 + m16] = acc[i][j][r];
    }
  }
}

// ---------------- 6b. tap gather: dg[o][p] = sum_tap y_pre[o*27+tap][p+shift] (zero bounds) ----------------
__global__ __launch_bounds__(256) void k_dgg(float* __restrict__ ws){
  int i = blockIdx.x*256 + threadIdx.x; // < 196608
  int b = blockIdx.y;
  int o = i >> 15;          // 0..5 -> but i<196608 so o<6? no: i<196608, i>>15 < 6 (o in 0..5 per b? 196608/32768=6) 
  // careful: dg layout is [o(3)][32768] per batch -> i in [0,98304): o = i>>15 (0..2), pos = i&32767
  if (i >= 98304) return;
  int pos = i & 32767;
  o = i >> 15;
  int d = pos>>10, h = (pos>>5)&31, w_ = pos&31;
  const float* yp = ws + OFF_YP + (size_t)b*3145728 + (size_t)o*27*32768;
  float s = 0.f;
  #pragma unroll
  for (int kd=0;kd<3;++kd){
    int gd = d+kd-1;
    if (gd < 0 || gd > 31) continue;
    #pragma unroll
    for (int kh=0;kh<3;++kh){
      int gh = h+kh-1;
      if (gh < 0 || gh > 31) continue;
      #pragma unroll
      for (int kw=0;kw<3;++kw){
        int gw = w_+kw-1;
        if (gw < 0 || gw > 31) continue;
        s += yp[(size_t)(kd*9+kh*3+kw)*32768 + gd*1024 + gh*32 + gw];
      }
    }
  }
  ws[OFF_DG + (size_t)b*98304 + i] = s;
}

// ---------------- 6c. fallback scalar dg conv (usePart==0 only, atomic into OFF_DG) ----------------
__global__ __launch_bounds__(256) void k_dg(const float* __restrict__ dgw, float* __restrict__ ws){
  int tile = blockIdx.x;        // 0..7
  int split = blockIdx.y;       // 0..31 (8 ci each)
  int b = blockIdx.z;
  int d0 = (tile>>1)*8, h0=(tile&1)*16;
  int tid = threadIdx.x;
  int wt = tid&1, hy=(tid>>1)&15, dx=tid>>5;
  int d = d0+dx, h = h0+hy, w0 = wt*16;
  int cbeg = split*8;
  __shared__ float wss[8][27][4];     // [ci][tap][{o0,o1,o2,pad}]
  for (int i=tid;i<864;i+=256){
    int ci = i/108; int r = i - ci*108; int tap = r>>2; int o = r&3;
    wss[ci][tap][o] = (o<3)? dgw[o*6912 + (cbeg+ci)*27 + tap] : 0.f;
  }
  __syncthreads();
  const u16* zp = (const u16*)(ws+OFF_Z) + (size_t)b*8388608;
  float acc[3][16];
  #pragma unroll
  for (int o=0;o<3;++o){
    #pragma unroll
    for (int j=0;j<16;++j) acc[o][j]=0.f;
  }
  for (int ci=0; ci<8; ++ci){
    const u16* zc = zp + (size_t)(cbeg+ci)*32768;
    #pragma unroll
    for (int kd=0;kd<3;++kd){
      int gd = d+kd-1;
      #pragma unroll
      for (int kh=0;kh<3;++kh){
        int gh = h+kh-1;
        bool rv = (gd>=0) & (gd<32) & (gh>=0) & (gh<32);
        const u16* rowp = zc + gd*1024 + gh*32 + w0;
        uint4 u0 = *(const uint4*)(rowp);
        uint4 u1 = *(const uint4*)(rowp+8);
        u16 le = (wt==0)? (u16)0 : rowp[-1];
        u16 ri = (wt==1)? (u16)0 : rowp[16];
        if (!rv){ u0 = make_uint4(0,0,0,0); u1 = make_uint4(0,0,0,0); le = 0; ri = 0; }
        float r[18];
        r[0]  = bf2f(le);
        r[1]  = bf2f((u16)(u0.x&0xffff)); r[2]  = bf2f((u16)(u0.x>>16));
        r[3]  = bf2f((u16)(u0.y&0xffff)); r[4]  = bf2f((u16)(u0.y>>16));
        r[5]  = bf2f((u16)(u0.z&0xffff)); r[6]  = bf2f((u16)(u0.z>>16));
        r[7]  = bf2f((u16)(u0.w&0xffff)); r[8]  = bf2f((u16)(u0.w>>16));
        r[9]  = bf2f((u16)(u1.x&0xffff)); r[10] = bf2f((u16)(u1.x>>16));
        r[11] = bf2f((u16)(u1.y&0xffff)); r[12] = bf2f((u16)(u1.y>>16));
        r[13] = bf2f((u16)(u1.z&0xffff)); r[14] = bf2f((u16)(u1.z>>16));
        r[15] = bf2f((u16)(u1.w&0xffff)); r[16] = bf2f((u16)(u1.w>>16));
        r[17] = bf2f(ri);
        #pragma unroll
        for (int kw=0;kw<3;++kw){
          float4 wv = *(const float4*)&wss[ci][kd*9+kh*3+kw][0];
          #pragma unroll
          for (int j=0;j<16;++j){
            acc[0][j]=fmaf(r[j+kw],wv.x,acc[0][j]);
            acc[1][j]=fmaf(r[j+kw],wv.y,acc[1][j]);
            acc[2][j]=fmaf(r[j+kw],wv.z,acc[2][j]);
          }
        }
      }
    }
  }
  float* op = ws + OFF_DG + (size_t)b*98304;
  #pragma unroll
  for (int o=0;o<3;++o){
    #pragma unroll
    for (int j=0;j<16;++j)
      atomicAdd(&op[o*32768 + d*1024 + h*32 + w0 + j], acc[o][j]);
  }
}

// ---------------- 7. upsample x2 nearest + 3x3x3 conv (3->3), pad 1 ----------------
__global__ __launch_bounds__(256) void k_up(const float* __restrict__ dgb, const float* __restrict__ nlw,
                                            const float* __restrict__ nlb, const float* __restrict__ ws,
                                            float* __restrict__ out){
  int b = blockIdx.y; int tileIdx = blockIdx.x;
  int zt0 = (tileIdx&7)*8, yt0 = ((tileIdx>>3)&7)*8, xt0 = (tileIdx>>6)*4;
  int sx0 = (xt0>>1)-1, sy0 = (yt0>>1)-1, sz0 = (zt0>>1)-1;
  __shared__ float ds[3][4][6][6];
  __shared__ float wl[243];
  const float* dgp = ws + OFF_DG + (size_t)b*98304;
  for (int i=threadIdx.x; i<432; i+=256){
    int ch = i/144; int r = i-ch*144; int sx=r/36; int rr=r-sx*36; int sy=rr/6; int sz=rr-sy*6;
    int gx = sx0+sx, gy = sy0+sy, gz = sz0+sz;
    float v=0.f;
    if (gx>=0&&gx<32&&gy>=0&&gy<32&&gz>=0&&gz<32) v = dgp[ch*32768 + gx*1024 + gy*32 + gz] + dgb[ch];
    ds[ch][sx][sy][sz] = v;
  }
  for (int i=threadIdx.x;i<243;i+=256) wl[i] = nlw[i];
  __syncthreads();
  int zt = threadIdx.x&7, yt=(threadIdx.x>>3)&7, xt=threadIdx.x>>6;
  int x = xt0+xt, y=yt0+yt, zc=zt0+zt;
  float a0=nlb[0], a1=nlb[1], a2=nlb[2];
  #pragma unroll
  for (int i=0;i<3;++i){
    #pragma unroll
    for (int kd=0;kd<3;++kd){
      int sxi = ((x+kd-1)>>1) - sx0;
      #pragma unroll
      for (int kh=0;kh<3;++kh){
        int syi = ((y+kh-1)>>1) - sy0;
        #pragma unroll
        for (int kw=0;kw<3;++kw){
          int szi = ((zc+kw-1)>>1) - sz0;
          float vv = ds[i][sxi][syi][szi];
          int tap = kd*9+kh*3+kw;
          a0 = fmaf(vv, wl[i*27+tap],      a0);
          a1 = fmaf(vv, wl[81+i*27+tap],   a1);
          a2 = fmaf(vv, wl[162+i*27+tap],  a2);
        }
      }
    }
  }
  size_t o0 = (size_t)b*786432 + (size_t)x*4096 + y*64 + zc;
  out[o0] = a0; out[o0+262144] = a1; out[o0+524288] = a2;
}

// ---------------- launch ----------------
extern "C" void kernel_launch(void* const* d_in, const int* in_sizes, int n_in,
                              void* d_out, int out_size, void* d_ws, size_t ws_size,
                              hipStream_t stream){
  const float* q    = (const float*)d_in[0];
  const float* k    = (const float*)d_in[1];
  const float* v    = (const float*)d_in[2];
  const float* gnw  = (const float*)d_in[3];
  const float* gnb  = (const float*)d_in[4];
  const float* outw = (const float*)d_in[5];
  const float* outb = (const float*)d_in[6];
  const float* dgw  = (const float*)d_in[7];
  const float* dgb  = (const float*)d_in[8];
  const float* nlw  = (const float*)d_in[9];
  const float* nlb  = (const float*)d_in[10];
  float* out = (float*)d_out;
  float* ws  = (float*)d_ws;
  int usePart = (ws_size >= (size_t)WS_PART_FLOATS*4) ? 1 : 0;

  (void)hipMemsetAsync(ws, 0, 139264, stream);                       // stats..ctx region
  if (!usePart)
    (void)hipMemsetAsync((void*)(ws + OFF_DG), 0, 196608*4, stream); // dg final (atomic fallback)

  k_stats   <<<dim3(1024),   dim3(512), 0, stream>>>(k,v,ws);
  k_finalize<<<dim3(1),      dim3(32),  0, stream>>>(ws);
  if (usePart) k_wt<<<dim3(96), dim3(256), 0, stream>>>(dgw, ws);
  k_ctx     <<<dim3(64,12),  dim3(256), 0, stream>>>(q,k,v,gnw,gnb,ws,usePart);
  if (usePart) k_ctxred<<<dim3(130), dim3(256), 0, stream>>>(ws);
  k_weff    <<<dim3(256,2),  dim3(256), 0, stream>>>(outw,outb,gnw,gnb,ws);
  k_z       <<<dim3(256,2,2),dim3(256), 36864, stream>>>(q,ws);
  if (usePart){
    k_dgm<<<dim3(256,2), dim3(256), 36864, stream>>>(ws);
    k_dgg<<<dim3(384,2), dim3(256), 0, stream>>>(ws);
  } else {
    k_dg <<<dim3(8,32,2), dim3(256), 0, stream>>>(dgw,ws);
  }
  k_up      <<<dim3(1024,2), dim3(256), 0, stream>>>(dgb,nlw,nlb,ws,out);
}